// Round 1
// baseline (211.513 us; speedup 1.0000x reference)
//
#include <hip/hip_runtime.h>
#include <stdint.h>

// HyperLatticeBlock: B=2,S=1024,D=1024,L=48,K=4
// tokens T=2048. Pipeline: gate(top4)->bucket->expert GEMM(bf16 MFMA)->combine->out_proj->LN
#define TT 2048
#define DD 1024
#define LL 48

typedef __attribute__((ext_vector_type(8))) short short8;
typedef __attribute__((ext_vector_type(4))) float f32x4;

static __device__ __forceinline__ unsigned int f2bf(float f) {
  union { float f; unsigned int u; } v; v.f = f;
  return (v.u + 0x7FFFu + ((v.u >> 16) & 1u)) >> 16;   // RNE f32->bf16 bits
}
static __device__ __forceinline__ unsigned int pack2(float a, float b) {
  return f2bf(a) | (f2bf(b) << 16);
}

// ---------------- gate: logits fp32, top-4, softmax, bucket scatter, x->bf16 ----------------
__global__ __launch_bounds__(256) void k_gate(
    const float* __restrict__ x, const float* __restrict__ gw,
    unsigned short* __restrict__ xb,
    int* __restrict__ counts, int* __restrict__ btok, float* __restrict__ bscore)
{
  __shared__ float xs[8][1024];
  __shared__ float lg[8][48];
  const int tid = threadIdx.x;
  const int t0 = blockIdx.x * 8;
  for (int u = tid; u < 2048; u += 256) {          // 8 rows x 256 float4
    int tok = u >> 8;
    int c = (u & 255) << 2;
    float4 v = *(const float4*)(x + (size_t)(t0 + tok) * DD + c);
    *(float4*)&xs[tok][c] = v;
    uint2 p; p.x = pack2(v.x, v.y); p.y = pack2(v.z, v.w);
    *(uint2*)(xb + (size_t)(t0 + tok) * DD + c) = p;
  }
  __syncthreads();
  const int lane = tid & 63, wid = tid >> 6;
  for (int li = 0; li < 12; ++li) {
    const int l = wid + (li << 2);
    const float4* gp = (const float4*)(gw + (size_t)l * DD);
    float4 g0 = gp[lane], g1 = gp[lane + 64], g2 = gp[lane + 128], g3 = gp[lane + 192];
    for (int tok = 0; tok < 8; ++tok) {
      const float4* xp = (const float4*)&xs[tok][0];
      float4 a0 = xp[lane], a1 = xp[lane + 64], a2 = xp[lane + 128], a3 = xp[lane + 192];
      float s = a0.x*g0.x + a0.y*g0.y + a0.z*g0.z + a0.w*g0.w
              + a1.x*g1.x + a1.y*g1.y + a1.z*g1.z + a1.w*g1.w
              + a2.x*g2.x + a2.y*g2.y + a2.z*g2.z + a2.w*g2.w
              + a3.x*g3.x + a3.y*g3.y + a3.z*g3.z + a3.w*g3.w;
      #pragma unroll
      for (int off = 32; off; off >>= 1) s += __shfl_down(s, off);
      if (lane == 0) lg[tok][l] = s;
    }
  }
  __syncthreads();
  if (tid < 8) {
    const int tok = tid;
    float v[4]; int id[4];
    unsigned long long taken = 0ull;
    for (int k = 0; k < 4; ++k) {
      float best = -3.4e38f; int bi = 0;
      for (int l = 0; l < 48; ++l) {
        float cand = lg[tok][l];
        if (!((taken >> l) & 1ull) && cand > best) { best = cand; bi = l; }
      }
      taken |= (1ull << bi); v[k] = best; id[k] = bi;
    }
    // softmax over descending top-4 (order inside top-4 is permutation-invariant downstream)
    float e0 = 1.0f;
    float e1 = expf(v[1] - v[0]);
    float e2 = expf(v[2] - v[0]);
    float e3 = expf(v[3] - v[0]);
    float inv = 1.0f / (e0 + e1 + e2 + e3);
    float sc[4] = { e0*inv, e1*inv, e2*inv, e3*inv };
    for (int k = 0; k < 4; ++k) {
      int pos = atomicAdd(&counts[id[k]], 1);
      btok[id[k] * TT + pos] = ((t0 + tok) << 2) | k;   // token*4 + k  (= sel row)
      bscore[id[k] * TT + pos] = sc[k];
    }
  }
}

// ---------------- expert GEMM: per (expert, m_tile, n_tile) 128x128, BK=32 ----------------
// OUT[t][e] = sum_d X[t][d] * W[l][d][e];  A = gathered bf16 x rows (k-contig),
// B = W converted fp32->bf16 inline, stored LDS-transposed [e][k] (k-contig).
__global__ __launch_bounds__(256, 2) void k_expert(
    const unsigned short* __restrict__ xb, const float* __restrict__ W,
    const int* __restrict__ counts, const int* __restrict__ btok,
    const float* __restrict__ bscore, float* __restrict__ sel)
{
  const int l = blockIdx.z;
  const int ncnt = counts[l];
  const int m0 = blockIdx.y * 128;
  if (m0 >= ncnt) return;
  const int n0 = blockIdx.x * 128;
  const int tid = threadIdx.x, lane = tid & 63, wid = tid >> 6;
  const int wr = wid >> 1, wc = wid & 1;

  __shared__ unsigned short As[128][32];
  __shared__ unsigned short Bs[128][32];   // [e_local][k]
  __shared__ int   toks[128];
  __shared__ float scs[128];

  if (tid < 128) {
    int r = m0 + tid;
    toks[tid] = (r < ncnt) ? btok[l * TT + r] : 0;
    scs[tid]  = (r < ncnt) ? bscore[l * TT + r] : 0.f;
  }
  __syncthreads();

  f32x4 acc[4][4];
  #pragma unroll
  for (int m = 0; m < 4; ++m)
    #pragma unroll
    for (int n = 0; n < 4; ++n)
      #pragma unroll
      for (int j = 0; j < 4; ++j) acc[m][n][j] = 0.f;

  const float* Wl = W + (size_t)l * (DD * DD);
  const int e_loc = tid & 127, half = tid >> 7;   // B staging: one column e, 16 d's
  const int ar = tid >> 2, aseg = tid & 3;        // A staging: 16B units

  for (int kk = 0; kk < DD; kk += 32) {
    int4 a0 = *(const int4*)(xb + (size_t)(toks[ar] >> 2)      * DD + kk + aseg * 8);
    int4 a1 = *(const int4*)(xb + (size_t)(toks[ar + 64] >> 2) * DD + kk + aseg * 8);
    const float* wp = Wl + (size_t)(kk + half * 16) * DD + n0 + e_loc;
    float wv[16];
    #pragma unroll
    for (int j = 0; j < 16; ++j) wv[j] = wp[(size_t)j * DD];
    __syncthreads();
    *(int4*)&As[ar][aseg * 8] = a0;
    *(int4*)&As[ar + 64][aseg * 8] = a1;
    unsigned int pw[8];
    #pragma unroll
    for (int j = 0; j < 8; ++j) pw[j] = pack2(wv[2 * j], wv[2 * j + 1]);
    *(int4*)&Bs[e_loc][half * 16]     = *(int4*)&pw[0];
    *(int4*)&Bs[e_loc][half * 16 + 8] = *(int4*)&pw[4];
    __syncthreads();
    short8 af[4], bf[4];
    #pragma unroll
    for (int m = 0; m < 4; ++m)
      af[m] = *(const short8*)&As[wr * 64 + m * 16 + (lane & 15)][(lane >> 4) * 8];
    #pragma unroll
    for (int n = 0; n < 4; ++n)
      bf[n] = *(const short8*)&Bs[wc * 64 + n * 16 + (lane & 15)][(lane >> 4) * 8];
    #pragma unroll
    for (int m = 0; m < 4; ++m)
      #pragma unroll
      for (int n = 0; n < 4; ++n)
        acc[m][n] = __builtin_amdgcn_mfma_f32_16x16x32_bf16(af[m], bf[n], acc[m][n], 0, 0, 0);
  }

  // epilogue: D[r][c]: c = lane&15 (e), r = (lane>>4)*4 + j  [m89-verified]
  #pragma unroll
  for (int m = 0; m < 4; ++m) {
    #pragma unroll
    for (int j = 0; j < 4; ++j) {
      const int r = wr * 64 + m * 16 + ((lane >> 4) << 2) + j;
      if (m0 + r < ncnt) {
        const float sc = scs[r];
        const size_t ob = (size_t)toks[r] * DD + n0 + wc * 64 + (lane & 15);
        #pragma unroll
        for (int n = 0; n < 4; ++n)
          sel[ob + n * 16] = acc[m][n][j] * sc;
      }
    }
  }
}

// ---------------- combine: lat_bf16[t][d] = sum_k sel[t*4+k][d] ----------------
__global__ __launch_bounds__(256) void k_combine(const float* __restrict__ sel,
                                                 unsigned short* __restrict__ lat)
{
  const size_t i = ((size_t)blockIdx.x * 256 + threadIdx.x) << 2;  // 4 elems
  const size_t t = i >> 10, d = i & 1023;
  const float* p = sel + ((t << 2) << 10) + d;
  float4 s0 = *(const float4*)(p);
  float4 s1 = *(const float4*)(p + 1024);
  float4 s2 = *(const float4*)(p + 2048);
  float4 s3 = *(const float4*)(p + 3072);
  float r0 = s0.x + s1.x + s2.x + s3.x;
  float r1 = s0.y + s1.y + s2.y + s3.y;
  float r2 = s0.z + s1.z + s2.z + s3.z;
  float r3 = s0.w + s1.w + s2.w + s3.w;
  uint2 pk; pk.x = pack2(r0, r1); pk.y = pack2(r2, r3);
  *(uint2*)(lat + i) = pk;
}

// ---------------- out_proj: y = x + lat @ out_w^T + b ----------------
// out_w is [e][d] row-major -> both operands k(d)-contiguous, no transpose needed.
__global__ __launch_bounds__(256, 2) void k_outproj(
    const unsigned short* __restrict__ lat, const float* __restrict__ W2,
    const float* __restrict__ xres, const float* __restrict__ bias,
    float* __restrict__ y)
{
  const int n0 = blockIdx.x * 128;   // e
  const int m0 = blockIdx.y * 128;   // t
  const int tid = threadIdx.x, lane = tid & 63, wid = tid >> 6;
  const int wr = wid >> 1, wc = wid & 1;
  __shared__ unsigned short As[128][32];
  __shared__ unsigned short Bs[128][32];
  f32x4 acc[4][4];
  #pragma unroll
  for (int m = 0; m < 4; ++m)
    #pragma unroll
    for (int n = 0; n < 4; ++n)
      #pragma unroll
      for (int j = 0; j < 4; ++j) acc[m][n][j] = 0.f;
  const int ar = tid >> 2, aseg = tid & 3;
  const int e2 = tid >> 1, h2 = tid & 1;
  for (int kk = 0; kk < DD; kk += 32) {
    int4 a0 = *(const int4*)(lat + (size_t)(m0 + ar) * DD + kk + aseg * 8);
    int4 a1 = *(const int4*)(lat + (size_t)(m0 + ar + 64) * DD + kk + aseg * 8);
    const float* wp = W2 + (size_t)(n0 + e2) * DD + kk + h2 * 16;
    float4 w0 = *(const float4*)(wp);
    float4 w1 = *(const float4*)(wp + 4);
    float4 w2 = *(const float4*)(wp + 8);
    float4 w3 = *(const float4*)(wp + 12);
    __syncthreads();
    *(int4*)&As[ar][aseg * 8] = a0;
    *(int4*)&As[ar + 64][aseg * 8] = a1;
    unsigned int pw[8] = { pack2(w0.x,w0.y), pack2(w0.z,w0.w), pack2(w1.x,w1.y), pack2(w1.z,w1.w),
                           pack2(w2.x,w2.y), pack2(w2.z,w2.w), pack2(w3.x,w3.y), pack2(w3.z,w3.w) };
    *(int4*)&Bs[e2][h2 * 16]     = *(int4*)&pw[0];
    *(int4*)&Bs[e2][h2 * 16 + 8] = *(int4*)&pw[4];
    __syncthreads();
    short8 af[4], bf[4];
    #pragma unroll
    for (int m = 0; m < 4; ++m)
      af[m] = *(const short8*)&As[wr * 64 + m * 16 + (lane & 15)][(lane >> 4) * 8];
    #pragma unroll
    for (int n = 0; n < 4; ++n)
      bf[n] = *(const short8*)&Bs[wc * 64 + n * 16 + (lane & 15)][(lane >> 4) * 8];
    #pragma unroll
    for (int m = 0; m < 4; ++m)
      #pragma unroll
      for (int n = 0; n < 4; ++n)
        acc[m][n] = __builtin_amdgcn_mfma_f32_16x16x32_bf16(af[m], bf[n], acc[m][n], 0, 0, 0);
  }
  #pragma unroll
  for (int m = 0; m < 4; ++m) {
    #pragma unroll
    for (int j = 0; j < 4; ++j) {
      const int t = m0 + wr * 64 + m * 16 + ((lane >> 4) << 2) + j;
      #pragma unroll
      for (int n = 0; n < 4; ++n) {
        const int e = n0 + wc * 64 + n * 16 + (lane & 15);
        y[(size_t)t * DD + e] = xres[(size_t)t * DD + e] + acc[m][n][j] + bias[e];
      }
    }
  }
}

// ---------------- LayerNorm ----------------
__global__ __launch_bounds__(256) void k_ln(const float* __restrict__ y,
    const float* __restrict__ g, const float* __restrict__ b, float* __restrict__ out)
{
  const int t = blockIdx.x, tid = threadIdx.x;
  float4 v = *(const float4*)(y + (size_t)t * DD + tid * 4);
  float s  = v.x + v.y + v.z + v.w;
  float ss = v.x*v.x + v.y*v.y + v.z*v.z + v.w*v.w;
  #pragma unroll
  for (int off = 32; off; off >>= 1) { s += __shfl_down(s, off); ss += __shfl_down(ss, off); }
  __shared__ float rs[8];
  const int wid = tid >> 6, lane = tid & 63;
  if (lane == 0) { rs[wid] = s; rs[wid + 4] = ss; }
  __syncthreads();
  float S  = rs[0] + rs[1] + rs[2] + rs[3];
  float SS = rs[4] + rs[5] + rs[6] + rs[7];
  float mu = S * (1.0f / DD);
  float var = SS * (1.0f / DD) - mu * mu;
  float inv = rsqrtf(var + 1e-5f);
  float4 gg = *(const float4*)(g + tid * 4);
  float4 bb = *(const float4*)(b + tid * 4);
  float4 o;
  o.x = gg.x * (v.x - mu) * inv + bb.x;
  o.y = gg.y * (v.y - mu) * inv + bb.y;
  o.z = gg.z * (v.z - mu) * inv + bb.z;
  o.w = gg.w * (v.w - mu) * inv + bb.w;
  *(float4*)(out + (size_t)t * DD + tid * 4) = o;
}

extern "C" void kernel_launch(void* const* d_in, const int* in_sizes, int n_in,
                              void* d_out, int out_size, void* d_ws, size_t ws_size,
                              hipStream_t stream) {
  (void)in_sizes; (void)n_in; (void)out_size;
  const float* x   = (const float*)d_in[0];
  const float* gw  = (const float*)d_in[1];
  const float* lw  = (const float*)d_in[2];
  const float* ow  = (const float*)d_in[3];
  const float* obv = (const float*)d_in[4];
  const float* lng = (const float*)d_in[5];
  const float* lnb = (const float*)d_in[6];
  float* out = (float*)d_out;

  // workspace layout (~48.8 MB needed)
  char* ws = (char*)d_ws;
  unsigned short* xb  = (unsigned short*)(ws);                    // 4 MB  bf16 x
  unsigned short* lat = (unsigned short*)(ws + (4u << 20));       // 4 MB  bf16 lattice_out
  float* y            = (float*)(ws + (8u << 20));                // 8 MB  pre-LN
  float* sel          = (float*)(ws + (16u << 20));               // 32 MB [T*4][D]
  int*   counts       = (int*)(ws + (48u << 20));                 // 192 B
  int*   btok         = (int*)(ws + (48u << 20) + 4096);          // 384 KB
  float* bscore       = (float*)(ws + (48u << 20) + 4096 + LL * TT * 4); // 384 KB
  if (ws_size < ((48u << 20) + 4096 + 2u * LL * TT * 4)) return;  // would corrupt -> bail (leaves poison)

  hipMemsetAsync(counts, 0, LL * sizeof(int), stream);
  k_gate<<<TT / 8, 256, 0, stream>>>(x, gw, xb, counts, btok, bscore);
  k_expert<<<dim3(8, 16, 48), 256, 0, stream>>>(xb, lw, counts, btok, bscore, sel);
  k_combine<<<TT * DD / (256 * 4), 256, 0, stream>>>(sel, lat);
  k_outproj<<<dim3(8, 16), 256, 0, stream>>>(lat, ow, x, obv, y);
  k_ln<<<TT, 256, 0, stream>>>(y, lng, lnb, out);
}